// Round 5
// baseline (579.439 us; speedup 1.0000x reference)
//
#include <hip/hip_runtime.h>
#include <hip/hip_bf16.h>

#define N_NODES 20000
#define N_EDGES 320000
#define ETILES 4

typedef __attribute__((ext_vector_type(8))) short short8;
typedef __attribute__((ext_vector_type(4))) float f32x4;

static __device__ __forceinline__ unsigned short f2bf(float f) {
  __hip_bfloat16 h = __float2bfloat16(f);
  union { __hip_bfloat16 h; unsigned short u; } cv; cv.h = h; return cv.u;
}

static __device__ __forceinline__ float bf2f(unsigned short u) {
  union { unsigned int u; float f; } cv; cv.u = ((unsigned int)u) << 16; return cv.f;
}

static __device__ __forceinline__ unsigned int pk2(float a, float b) {
  return (unsigned int)f2bf(a) | ((unsigned int)f2bf(b) << 16);
}

// tanh-form GELU: x * sigmoid(2*sqrt(2/pi)*(x + 0.044715 x^3)); max |err| vs erf ~3e-3.
// z is pre-scaled by log2(e) so sigma(2u) = exp2(z)/(1+exp2(z)) needs one v_exp_f32.
static __device__ __forceinline__ float gelu_f(float x) {
  float z = x * (2.3022082f + 0.1029432f * x * x);   // 2*log2e*sqrt(2/pi)*(1, 0.044715)
  z = fminf(fmaxf(z, -30.0f), 30.0f);
#if __has_builtin(__builtin_amdgcn_exp2f)
  float t = __builtin_amdgcn_exp2f(z);
#else
  float t = exp2f(z);
#endif
#if __has_builtin(__builtin_amdgcn_rcpf)
  return x * t * __builtin_amdgcn_rcpf(1.0f + t);
#else
  return x * t / (1.0f + t);
#endif
}

// XOR swizzle for bf16 tiles with 512B/1024B row stride (16B granule spread)
#define SWZ(row, byteoff) ((byteoff) ^ (((row) & 7) << 4))
// fp32 U tile swizzle keyed off address bits
#define SWZU(b) ((b) ^ ((((b) >> 8) & 7) << 4))

// ---------------------------------------------------------------- zero S + cnt
__global__ void zero_kernel(float4* __restrict__ S4, int4* __restrict__ cnt4) {
  int idx = blockIdx.x * blockDim.x + threadIdx.x;
  S4[idx] = make_float4(0.f, 0.f, 0.f, 0.f);
  if (idx < N_NODES / 4) cnt4[idx] = make_int4(0, 0, 0, 0);
}

// ---------------------------------------------------------------- weight pack
// Pack W[K][Nc] (row-major f32) into bf16 MFMA-B-fragment order:
// P[(cf*(K/32)+t)*512 + l*8 + i] = W[t*32 + (l>>4)*8 + i][cf*16 + (l&15)]
__global__ void pack_kernel(const float* __restrict__ W1m, const float* __restrict__ W2m,
                            const float* __restrict__ W1u, const float* __restrict__ W2u,
                            unsigned short* __restrict__ P1m, unsigned short* __restrict__ P2m,
                            unsigned short* __restrict__ P1u, unsigned short* __restrict__ P2u) {
  int idx = blockIdx.x * blockDim.x + threadIdx.x;
  const float* W; unsigned short* P; int K, Nc, local;
  if (idx < 65536)        { W = W1m; P = P1m; K = 256; Nc = 256; local = idx; }
  else if (idx < 131072)  { W = W2m; P = P2m; K = 256; Nc = 256; local = idx - 65536; }
  else if (idx < 262144)  { W = W1u; P = P1u; K = 256; Nc = 512; local = idx - 131072; }
  else                    { W = W2u; P = P2u; K = 512; Nc = 256; local = idx - 262144; }
  int frag = local >> 9, wi = local & 511;
  int l = wi >> 3, i = wi & 7;
  int kf = K >> 5;
  int cf = frag / kf, t = frag % kf;
  int k = t * 32 + (l >> 4) * 8 + i;
  int n = cf * 16 + (l & 15);
  P[local] = f2bf(W[(size_t)k * Nc + n]);
}

// ---------------------------------------------------------------- histogram
__global__ void hist_kernel(const int* __restrict__ dst, int* __restrict__ cnt) {
  int e = blockIdx.x * blockDim.x + threadIdx.x;
  atomicAdd(&cnt[dst[e]], 1);
}

// ---------------------------------------------------------------- prefix scan (1 block, 1024 thr)
__global__ __launch_bounds__(1024) void scan_kernel(const int* __restrict__ cnt,
                                                    int* __restrict__ rptr,
                                                    int* __restrict__ cur) {
  __shared__ int sums[1024];
  const int t = threadIdx.x;
  const int base = t * 20;
  int local[20];
  int s = 0;
#pragma unroll
  for (int i = 0; i < 20; ++i) {
    int idx = base + i;
    int v = (idx < N_NODES) ? cnt[idx] : 0;
    local[i] = s;
    s += v;
  }
  int v = s;
  sums[t] = v;
  for (int off = 1; off < 1024; off <<= 1) {
    __syncthreads();
    int o = (t >= off) ? sums[t - off] : 0;
    __syncthreads();
    v += o;
    sums[t] = v;
  }
  int excl = v - s;
#pragma unroll
  for (int i = 0; i < 20; ++i) {
    int idx = base + i;
    if (idx < N_NODES) { int p = excl + local[i]; rptr[idx] = p; cur[idx] = p; }
  }
  if (t == 1023) rptr[N_NODES] = v;
}

// ---------------------------------------------------------------- scatter perm
__global__ void scatter_kernel(const int* __restrict__ dst, int* __restrict__ cur,
                               int* __restrict__ perm) {
  int e = blockIdx.x * blockDim.x + threadIdx.x;
  int d = dst[e];
  int pos = atomicAdd(&cur[d], 1);
  perm[pos] = e;
}

// ---------------------------------------------------------------- edge kernel
// 4 dst-sorted 64-edge tiles per block, 4 waves. Register-staged prefetch (T14):
// next tile's gathers issued under current tile's MFMA+gelu+reduction.
// h = node[src]+eemb -> LDS bf16 -> MFMA(W1m)+b1m -> gelu -> messages back to LDS
// -> per-column segmented reduction over sorted rows -> ~5 coalesced atomic
// row-flushes per tile.
__global__ __launch_bounds__(256) void edge_kernel(
    const float* __restrict__ node, const float* __restrict__ eemb,
    const int* __restrict__ src, const int* __restrict__ dst,
    const int* __restrict__ perm,
    const unsigned short* __restrict__ P1m, const float* __restrict__ b1m,
    float* __restrict__ S) {
  __shared__ unsigned short tA[64 * 256];
  __shared__ int dstS[64];
  const int tid = threadIdx.x;
  const int r = tid >> 2, cs = (tid & 3) * 64;
  const int w = tid >> 6, l = tid & 63, lr = l & 15, lh = l >> 4;
  const int base = blockIdx.x * (64 * ETILES);

  // prefetch all tile ids up-front (kills dependent-load chains at issue time)
  int eId[ETILES], sId[ETILES], dId[ETILES];
#pragma unroll
  for (int t = 0; t < ETILES; ++t) eId[t] = perm[base + t * 64 + r];
#pragma unroll
  for (int t = 0; t < ETILES; ++t) { sId[t] = src[eId[t]]; dId[t] = dst[eId[t]]; }

  float bias_c[4];
#pragma unroll
  for (int c = 0; c < 4; ++c) bias_c[c] = b1m[w * 64 + c * 16 + lr];

  float4 fa[8], fb[8];  // in-flight gather regs (half a tile-row: 32 cols)
  uint4 stg[8];         // packed staging for next tile (64 cols)

  // issue gathers for tile t, half h (cols cs+32h .. cs+32h+31)
  auto issue_half = [&](int t, int h) {
    const float* ep = eemb + (size_t)eId[t] * 256 + cs + h * 32;
    const float* np = node + (size_t)sId[t] * 256 + cs + h * 32;
#pragma unroll
    for (int j = 0; j < 8; ++j) {
      fa[j] = *(const float4*)(ep + j * 4);
      fb[j] = *(const float4*)(np + j * 4);
    }
  };
  // add + bf16-pack fa/fb -> 4 uint4
  auto pack_half = [&](uint4* o) {
#pragma unroll
    for (int j = 0; j < 4; ++j) {
      float4 a = fa[2 * j], b = fb[2 * j], c = fa[2 * j + 1], d = fb[2 * j + 1];
      o[j].x = pk2(a.x + b.x, a.y + b.y);
      o[j].y = pk2(a.z + b.z, a.w + b.w);
      o[j].z = pk2(c.x + d.x, c.y + d.y);
      o[j].w = pk2(c.z + d.z, c.w + d.w);
    }
  };
  auto write_stage = [&](int t) {
#pragma unroll
    for (int i = 0; i < 8; ++i)
      *(uint4*)((char*)tA + SWZ(r, r * 512 + (cs + i * 8) * 2)) = stg[i];
    if ((tid & 3) == 0) dstS[r] = dId[t];
  };

  // prologue: stage tile 0 (unavoidably serial)
  issue_half(0, 0); pack_half(&stg[0]);
  issue_half(0, 1); pack_half(&stg[4]);
  write_stage(0);
  __syncthreads();

  for (int t = 0; t < ETILES; ++t) {
    const bool last = (t == ETILES - 1);
    if (!last) issue_half(t + 1, 0);  // latency hides under MFMA

    // ---- MFMA: h1 = (tile) @ W1m + b1m
    f32x4 acc[4][4];
#pragma unroll
    for (int c = 0; c < 4; ++c)
#pragma unroll
      for (int r4 = 0; r4 < 4; ++r4) acc[r4][c] = f32x4{bias_c[c], bias_c[c], bias_c[c], bias_c[c]};
#pragma unroll
    for (int kt = 0; kt < 8; ++kt) {
      short8 af[4], bfr[4];
#pragma unroll
      for (int r4 = 0; r4 < 4; ++r4) {
        int row = r4 * 16 + lr;
        af[r4] = *(const short8*)((const char*)tA + SWZ(row, row * 512 + kt * 64 + lh * 16));
      }
#pragma unroll
      for (int c = 0; c < 4; ++c)
        bfr[c] = *(const short8*)(P1m + (size_t)(((w * 4 + c) * 8 + kt) * 512 + l * 8));
#pragma unroll
      for (int r4 = 0; r4 < 4; ++r4)
#pragma unroll
        for (int c = 0; c < 4; ++c)
          acc[r4][c] = __builtin_amdgcn_mfma_f32_16x16x32_bf16(af[r4], bfr[c], acc[r4][c], 0, 0, 0);
    }
    __syncthreads();  // B1: all A-frag reads of tA done

    if (!last) { pack_half(&stg[0]); issue_half(t + 1, 1); }  // latency hides under gelu+reduction

    // ---- gelu -> messages back into tA (bf16)
#pragma unroll
    for (int r4 = 0; r4 < 4; ++r4)
#pragma unroll
      for (int c = 0; c < 4; ++c) {
        int col = w * 64 + c * 16 + lr;
#pragma unroll
        for (int j = 0; j < 4; ++j) {
          int row = r4 * 16 + lh * 4 + j;
          *(unsigned short*)((char*)tA + SWZ(row, row * 512 + col * 2)) =
              f2bf(gelu_f(acc[r4][c][j]));
        }
      }
    __syncthreads();  // B2: messages visible

    // ---- segmented column reduction over sorted rows (branch is wave-uniform)
    {
      const int col = tid;
      float run = 0.f;
      int cur = dstS[0];
#pragma unroll 8
      for (int row = 0; row < 64; ++row) {
        int d = dstS[row];
        float v = bf2f(*(const unsigned short*)((const char*)tA + SWZ(row, row * 512 + col * 2)));
        if (d != cur) {
          atomicAdd(&S[(size_t)cur * 256 + col], run);
          run = 0.f;
          cur = d;
        }
        run += v;
      }
      atomicAdd(&S[(size_t)cur * 256 + col], run);
    }

    if (!last) {
      pack_half(&stg[4]);
      __syncthreads();  // B3: message reads done everywhere
      write_stage(t + 1);
      __syncthreads();  // B4: staging visible
    }
  }
}

// ---------------------------------------------------------------- node kernel
// 64 nodes/block: A2 = S/max(deg,1); agg = A2@W2m + (deg>0)b2m;
// H = gelu(agg@W1u + b1u); U = H@W2u + b2u; out = LN(node + U)*gamma + beta.
__global__ __launch_bounds__(256) void node_kernel(
    const float* __restrict__ node, const float* __restrict__ S, const int* __restrict__ rptr,
    const unsigned short* __restrict__ P2m, const float* __restrict__ b2m,
    const unsigned short* __restrict__ P1u, const float* __restrict__ b1u,
    const unsigned short* __restrict__ P2u, const float* __restrict__ b2u,
    const float* __restrict__ gamma, const float* __restrict__ beta,
    float* __restrict__ out) {
  __shared__ unsigned short tAB[2][64 * 256];  // 64 KB: [0]=A2, [1]=agg; reused as fp32 U
  __shared__ unsigned short tH[64 * 512];      // 64 KB
  __shared__ float fmu[64], frs[64], fflag[64];
  float* tU = (float*)tAB;
  const int tid = threadIdx.x;
  const int n0 = blockIdx.x * 64;
  const int r = tid >> 2;
  const int cs = (tid & 3) * 64;
  const int n = n0 + r;
  const bool valid = n < N_NODES;
  {
    int dgi = valid ? (rptr[n + 1] - rptr[n]) : 0;
    float dg = (float)dgi;
    float rec = 1.0f / fmaxf(dg, 1.0f);
    if ((tid & 3) == 0) fflag[r] = (dgi > 0) ? 1.0f : 0.0f;
    const float4* sp = (const float4*)(S + (size_t)n * 256 + cs);
#pragma unroll
    for (int i = 0; i < 8; ++i) {
      float4 a = valid ? sp[2 * i]     : make_float4(0.f, 0.f, 0.f, 0.f);
      float4 b = valid ? sp[2 * i + 1] : make_float4(0.f, 0.f, 0.f, 0.f);
      uint4 p;
      p.x = pk2(a.x * rec, a.y * rec);
      p.y = pk2(a.z * rec, a.w * rec);
      p.z = pk2(b.x * rec, b.y * rec);
      p.w = pk2(b.z * rec, b.w * rec);
      *(uint4*)((char*)tAB[0] + SWZ(r, r * 512 + (cs + i * 8) * 2)) = p;
    }
  }
  __syncthreads();
  const int w = tid >> 6, l = tid & 63, lr = l & 15, lh = l >> 4;

  // ---- GEMM1: agg = A2 @ W2m + flag*b2m -> tAB[1] (bf16)
  {
    f32x4 acc[4][4];
#pragma unroll
    for (int r4 = 0; r4 < 4; ++r4)
#pragma unroll
      for (int c = 0; c < 4; ++c) acc[r4][c] = f32x4{0.f, 0.f, 0.f, 0.f};
#pragma unroll
    for (int t = 0; t < 8; ++t) {
      short8 af[4], bfr[4];
#pragma unroll
      for (int r4 = 0; r4 < 4; ++r4) {
        int row = r4 * 16 + lr;
        af[r4] = *(const short8*)((const char*)tAB[0] + SWZ(row, row * 512 + t * 64 + lh * 16));
      }
#pragma unroll
      for (int c = 0; c < 4; ++c)
        bfr[c] = *(const short8*)(P2m + (size_t)(((w * 4 + c) * 8 + t) * 512 + l * 8));
#pragma unroll
      for (int r4 = 0; r4 < 4; ++r4)
#pragma unroll
        for (int c = 0; c < 4; ++c)
          acc[r4][c] = __builtin_amdgcn_mfma_f32_16x16x32_bf16(af[r4], bfr[c], acc[r4][c], 0, 0, 0);
    }
#pragma unroll
    for (int r4 = 0; r4 < 4; ++r4)
#pragma unroll
      for (int c = 0; c < 4; ++c) {
        int col = w * 64 + c * 16 + lr;
        float bm = b2m[col];
#pragma unroll
        for (int j = 0; j < 4; ++j) {
          int row = r4 * 16 + lh * 4 + j;
          float v = acc[r4][c][j] + fflag[row] * bm;
          *(unsigned short*)((char*)tAB[1] + SWZ(row, row * 512 + col * 2)) = f2bf(v);
        }
      }
  }
  __syncthreads();

  // ---- GEMM2: H = gelu(agg @ W1u + b1u) -> tH (64x512 bf16)
  {
    f32x4 acc[4][8];
#pragma unroll
    for (int r4 = 0; r4 < 4; ++r4)
#pragma unroll
      for (int c = 0; c < 8; ++c) acc[r4][c] = f32x4{0.f, 0.f, 0.f, 0.f};
#pragma unroll
    for (int t = 0; t < 8; ++t) {
      short8 af[4], bfr[8];
#pragma unroll
      for (int r4 = 0; r4 < 4; ++r4) {
        int row = r4 * 16 + lr;
        af[r4] = *(const short8*)((const char*)tAB[1] + SWZ(row, row * 512 + t * 64 + lh * 16));
      }
#pragma unroll
      for (int c = 0; c < 8; ++c)
        bfr[c] = *(const short8*)(P1u + (size_t)(((w * 8 + c) * 8 + t) * 512 + l * 8));
#pragma unroll
      for (int r4 = 0; r4 < 4; ++r4)
#pragma unroll
        for (int c = 0; c < 8; ++c)
          acc[r4][c] = __builtin_amdgcn_mfma_f32_16x16x32_bf16(af[r4], bfr[c], acc[r4][c], 0, 0, 0);
    }
#pragma unroll
    for (int r4 = 0; r4 < 4; ++r4)
#pragma unroll
      for (int c = 0; c < 8; ++c) {
        int col = w * 128 + c * 16 + lr;
        float b1 = b1u[col];
#pragma unroll
        for (int j = 0; j < 4; ++j) {
          int row = r4 * 16 + lh * 4 + j;
          float v = gelu_f(acc[r4][c][j] + b1);
          *(unsigned short*)((char*)tH + SWZ(row, row * 1024 + col * 2)) = f2bf(v);
        }
      }
  }
  __syncthreads();

  // ---- GEMM3: U = H @ W2u + b2u -> tU (fp32, SWZU)  [tAB dead -> reuse as tU]
  {
    f32x4 acc[4][4];
#pragma unroll
    for (int r4 = 0; r4 < 4; ++r4)
#pragma unroll
      for (int c = 0; c < 4; ++c) acc[r4][c] = f32x4{0.f, 0.f, 0.f, 0.f};
#pragma unroll
    for (int t = 0; t < 16; ++t) {
      short8 af[4], bfr[4];
#pragma unroll
      for (int r4 = 0; r4 < 4; ++r4) {
        int row = r4 * 16 + lr;
        af[r4] = *(const short8*)((const char*)tH + SWZ(row, row * 1024 + t * 64 + lh * 16));
      }
#pragma unroll
      for (int c = 0; c < 4; ++c)
        bfr[c] = *(const short8*)(P2u + (size_t)(((w * 4 + c) * 16 + t) * 512 + l * 8));
#pragma unroll
      for (int r4 = 0; r4 < 4; ++r4)
#pragma unroll
        for (int c = 0; c < 4; ++c)
          acc[r4][c] = __builtin_amdgcn_mfma_f32_16x16x32_bf16(af[r4], bfr[c], acc[r4][c], 0, 0, 0);
    }
#pragma unroll
    for (int r4 = 0; r4 < 4; ++r4)
#pragma unroll
      for (int c = 0; c < 4; ++c) {
        int col = w * 64 + c * 16 + lr;
        float b2 = b2u[col];
#pragma unroll
        for (int j = 0; j < 4; ++j) {
          int row = r4 * 16 + lh * 4 + j;
          *(float*)((char*)tU + SWZU(row * 1024 + col * 4)) = acc[r4][c][j] + b2;
        }
      }
  }
  __syncthreads();

  // ---- residual + LayerNorm stats
  {
    float sum = 0.f, sq = 0.f;
#pragma unroll
    for (int i = 0; i < 16; ++i) {
      int byte = SWZU(r * 1024 + (cs + i * 4) * 4);
      float4 v = *(float4*)((char*)tU + byte);
      if (valid) {
        const float4 nb = *(const float4*)(node + (size_t)n * 256 + cs + i * 4);
        v.x += nb.x; v.y += nb.y; v.z += nb.z; v.w += nb.w;
        *(float4*)((char*)tU + byte) = v;
      }
      sum += v.x + v.y + v.z + v.w;
      sq += v.x * v.x + v.y * v.y + v.z * v.z + v.w * v.w;
    }
    sum += __shfl_xor(sum, 1); sum += __shfl_xor(sum, 2);
    sq  += __shfl_xor(sq, 1);  sq  += __shfl_xor(sq, 2);
    if ((tid & 3) == 0) {
      float mu = sum * (1.0f / 256.0f);
      fmu[r] = mu;
      frs[r] = rsqrtf(fmaxf(sq * (1.0f / 256.0f) - mu * mu, 0.0f) + 1e-5f);
    }
  }
  __syncthreads();
#pragma unroll
  for (int i = 0; i < 16; ++i) {
    int f4 = i * 256 + tid;
    int row = f4 >> 6;
    int c4 = f4 & 63;
    int nn = n0 + row;
    if (nn < N_NODES) {
      float4 v = *(float4*)((char*)tU + SWZU(row * 1024 + c4 * 16));
      float mu = fmu[row], rs = frs[row];
      float4 g  = *(const float4*)(gamma + c4 * 4);
      float4 bt = *(const float4*)(beta + c4 * 4);
      float4 o;
      o.x = (v.x - mu) * rs * g.x + bt.x;
      o.y = (v.y - mu) * rs * g.y + bt.y;
      o.z = (v.z - mu) * rs * g.z + bt.z;
      o.w = (v.w - mu) * rs * g.w + bt.w;
      *(float4*)(out + (size_t)nn * 256 + c4 * 4) = o;
    }
  }
}

// ---------------------------------------------------------------- launch
extern "C" void kernel_launch(void* const* d_in, const int* in_sizes, int n_in,
                              void* d_out, int out_size, void* d_ws, size_t ws_size,
                              hipStream_t stream) {
  const float* node = (const float*)d_in[0];
  const int* eidx = (const int*)d_in[1];   // harness delivers integer inputs as int32
  const float* eemb = (const float*)d_in[2];
  const float* W1m = (const float*)d_in[3];
  const float* b1m = (const float*)d_in[4];
  const float* W2m = (const float*)d_in[5];
  const float* b2m = (const float*)d_in[6];
  const float* W1u = (const float*)d_in[7];
  const float* b1u = (const float*)d_in[8];
  const float* W2u = (const float*)d_in[9];
  const float* b2u = (const float*)d_in[10];
  const float* gamma = (const float*)d_in[11];
  const float* beta = (const float*)d_in[12];
  float* out = (float*)d_out;  // doubles as the scatter accumulator S [N,256] f32

  char* ws = (char*)d_ws;
  int* cnt  = (int*)ws;                                   // 80000 B
  int* rptr = (int*)(ws + 81920);                         // 80004 B
  int* cur  = (int*)(ws + 163840);                        // 80000 B
  int* perm = (int*)(ws + 245760);                        // 1280000 B
  unsigned short* P1m = (unsigned short*)(ws + 1525760);  // 131072 B
  unsigned short* P2m = (unsigned short*)(ws + 1656832);  // 131072 B
  unsigned short* P1u = (unsigned short*)(ws + 1787904);  // 262144 B
  unsigned short* P2u = (unsigned short*)(ws + 2050048);  // 262144 B
  const int* src = eidx;
  const int* dst = eidx + N_EDGES;

  zero_kernel<<<N_NODES * 64 / 256, 256, 0, stream>>>((float4*)out, (int4*)cnt);
  pack_kernel<<<393216 / 256, 256, 0, stream>>>(W1m, W2m, W1u, W2u, P1m, P2m, P1u, P2u);
  hist_kernel<<<N_EDGES / 256, 256, 0, stream>>>(dst, cnt);
  scan_kernel<<<1, 1024, 0, stream>>>(cnt, rptr, cur);
  scatter_kernel<<<N_EDGES / 256, 256, 0, stream>>>(dst, cur, perm);
  edge_kernel<<<N_EDGES / (64 * ETILES), 256, 0, stream>>>(node, eemb, src, dst, perm, P1m, b1m, out);
  node_kernel<<<(N_NODES + 63) / 64, 256, 0, stream>>>(node, out, rptr, P2m, b2m,
                                                       P1u, b1u, P2u, b2u, gamma, beta, out);
}

// Round 6
// 341.048 us; speedup vs baseline: 1.6990x; 1.6990x over previous
//
#include <hip/hip_runtime.h>
#include <hip/hip_bf16.h>

#define N_NODES 20000
#define N_EDGES 320000

typedef __attribute__((ext_vector_type(8))) short short8;
typedef __attribute__((ext_vector_type(4))) float f32x4;

static __device__ __forceinline__ unsigned short f2bf(float f) {
  __hip_bfloat16 h = __float2bfloat16(f);
  union { __hip_bfloat16 h; unsigned short u; } cv; cv.h = h; return cv.u;
}

static __device__ __forceinline__ float bf2f(unsigned short u) {
  union { unsigned int u; float f; } cv; cv.u = ((unsigned int)u) << 16; return cv.f;
}

static __device__ __forceinline__ unsigned int pk2(float a, float b) {
  return (unsigned int)f2bf(a) | ((unsigned int)f2bf(b) << 16);
}

// tanh-form GELU via one v_exp_f32: x * sigmoid(2*sqrt(2/pi)*(x+0.044715x^3)).
// max |err| vs exact-erf gelu ~3e-3 (threshold margin is 6x).
static __device__ __forceinline__ float gelu_f(float x) {
  float z = x * (2.3022082f + 0.1029432f * x * x);  // pre-scaled by log2(e)
  z = fminf(fmaxf(z, -30.0f), 30.0f);
  float t = exp2f(z);
  return x * t * __frcp_rn(1.0f + t);
}

// XOR swizzle for bf16 tiles with 512B/1024B row stride (16B granule spread)
#define SWZ(row, byteoff) ((byteoff) ^ (((row) & 7) << 4))
// fp32 U tile swizzle keyed off address bits
#define SWZU(b) ((b) ^ ((((b) >> 8) & 7) << 4))

// ---------------------------------------------------------------- zero S + cnt
__global__ void zero_kernel(float4* __restrict__ S4, int4* __restrict__ cnt4) {
  int idx = blockIdx.x * blockDim.x + threadIdx.x;
  S4[idx] = make_float4(0.f, 0.f, 0.f, 0.f);
  if (idx < N_NODES / 4) cnt4[idx] = make_int4(0, 0, 0, 0);
}

// ---------------------------------------------------------------- weight pack
// Pack W[K][Nc] (row-major f32) into bf16 MFMA-B-fragment order:
// P[(cf*(K/32)+t)*512 + l*8 + i] = W[t*32 + (l>>4)*8 + i][cf*16 + (l&15)]
__global__ void pack_kernel(const float* __restrict__ W1m, const float* __restrict__ W2m,
                            const float* __restrict__ W1u, const float* __restrict__ W2u,
                            unsigned short* __restrict__ P1m, unsigned short* __restrict__ P2m,
                            unsigned short* __restrict__ P1u, unsigned short* __restrict__ P2u) {
  int idx = blockIdx.x * blockDim.x + threadIdx.x;
  const float* W; unsigned short* P; int K, Nc, local;
  if (idx < 65536)        { W = W1m; P = P1m; K = 256; Nc = 256; local = idx; }
  else if (idx < 131072)  { W = W2m; P = P2m; K = 256; Nc = 256; local = idx - 65536; }
  else if (idx < 262144)  { W = W1u; P = P1u; K = 256; Nc = 512; local = idx - 131072; }
  else                    { W = W2u; P = P2u; K = 512; Nc = 256; local = idx - 262144; }
  int frag = local >> 9, wi = local & 511;
  int l = wi >> 3, i = wi & 7;
  int kf = K >> 5;
  int cf = frag / kf, t = frag % kf;
  int k = t * 32 + (l >> 4) * 8 + i;
  int n = cf * 16 + (l & 15);
  P[local] = f2bf(W[(size_t)k * Nc + n]);
}

// ---------------------------------------------------------------- histogram
__global__ void hist_kernel(const int* __restrict__ dst, int* __restrict__ cnt) {
  int e = blockIdx.x * blockDim.x + threadIdx.x;
  atomicAdd(&cnt[dst[e]], 1);
}

// ---------------------------------------------------------------- prefix scan (1 block, 1024 thr)
__global__ __launch_bounds__(1024) void scan_kernel(const int* __restrict__ cnt,
                                                    int* __restrict__ rptr,
                                                    int* __restrict__ cur) {
  __shared__ int sums[1024];
  const int t = threadIdx.x;
  const int base = t * 20;
  int local[20];
  int s = 0;
#pragma unroll
  for (int i = 0; i < 20; ++i) {
    int idx = base + i;
    int v = (idx < N_NODES) ? cnt[idx] : 0;
    local[i] = s;
    s += v;
  }
  int v = s;
  sums[t] = v;
  for (int off = 1; off < 1024; off <<= 1) {
    __syncthreads();
    int o = (t >= off) ? sums[t - off] : 0;
    __syncthreads();
    v += o;
    sums[t] = v;
  }
  int excl = v - s;
#pragma unroll
  for (int i = 0; i < 20; ++i) {
    int idx = base + i;
    if (idx < N_NODES) { int p = excl + local[i]; rptr[idx] = p; cur[idx] = p; }
  }
  if (t == 1023) rptr[N_NODES] = v;
}

// ---------------------------------------------------------------- scatter perm
__global__ void scatter_kernel(const int* __restrict__ dst, int* __restrict__ cur,
                               int* __restrict__ perm) {
  int e = blockIdx.x * blockDim.x + threadIdx.x;
  int d = dst[e];
  int pos = atomicAdd(&cur[d], 1);
  perm[pos] = e;
}

// ---------------------------------------------------------------- edge kernel
// 64 dst-sorted edges/block, 4 waves, LDS 33KB -> 4 blocks/CU (16 waves/CU:
// latency hiding comes from cross-block TLP, NOT per-wave register pipelines —
// round-5 lesson: VGPR-staged prefetch cut occupancy 3x and regressed 1.8x).
// h = node[src]+eemb -> LDS bf16 -> MFMA(W1m)+b1m -> gelu -> messages to LDS
// -> two independent 32-row segmented column reductions -> coalesced atomic
// row-flushes per dst segment.
__global__ __launch_bounds__(256) void edge_kernel(
    const float* __restrict__ node, const float* __restrict__ eemb,
    const int* __restrict__ src, const int* __restrict__ dst,
    const int* __restrict__ perm,
    const unsigned short* __restrict__ P1m, const float* __restrict__ b1m,
    float* __restrict__ S) {
  __shared__ unsigned short tA[64 * 256];
  __shared__ int dstS[64];
  const int tid = threadIdx.x;
  const int e0 = blockIdx.x * 64;
  {
    const int r = tid >> 2;
    const int cs = (tid & 3) * 64;
    const int e = perm[e0 + r];
    const int se = src[e];
    if ((tid & 3) == 0) dstS[r] = dst[e];
    const float* ep = eemb + (size_t)e * 256 + cs;
    const float* np = node + (size_t)se * 256 + cs;
#pragma unroll
    for (int i = 0; i < 8; ++i) {
      float4 a = *(const float4*)(ep + i * 8);
      float4 b = *(const float4*)(np + i * 8);
      float4 c = *(const float4*)(ep + i * 8 + 4);
      float4 d = *(const float4*)(np + i * 8 + 4);
      uint4 p;
      p.x = pk2(a.x + b.x, a.y + b.y);
      p.y = pk2(a.z + b.z, a.w + b.w);
      p.z = pk2(c.x + d.x, c.y + d.y);
      p.w = pk2(c.z + d.z, c.w + d.w);
      *(uint4*)((char*)tA + SWZ(r, r * 512 + (cs + i * 8) * 2)) = p;
    }
  }
  __syncthreads();

  const int w = tid >> 6, l = tid & 63;
  const int lr = l & 15, lh = l >> 4;
  f32x4 acc[4][4];
#pragma unroll
  for (int c = 0; c < 4; ++c) {
    float bb = b1m[w * 64 + c * 16 + lr];
#pragma unroll
    for (int r4 = 0; r4 < 4; ++r4) acc[r4][c] = f32x4{bb, bb, bb, bb};
  }
#pragma unroll
  for (int t = 0; t < 8; ++t) {
    short8 af[4], bfr[4];
#pragma unroll
    for (int r4 = 0; r4 < 4; ++r4) {
      int row = r4 * 16 + lr;
      af[r4] = *(const short8*)((const char*)tA + SWZ(row, row * 512 + t * 64 + lh * 16));
    }
#pragma unroll
    for (int c = 0; c < 4; ++c)
      bfr[c] = *(const short8*)(P1m + (size_t)(((w * 4 + c) * 8 + t) * 512 + l * 8));
#pragma unroll
    for (int r4 = 0; r4 < 4; ++r4)
#pragma unroll
      for (int c = 0; c < 4; ++c)
        acc[r4][c] = __builtin_amdgcn_mfma_f32_16x16x32_bf16(af[r4], bfr[c], acc[r4][c], 0, 0, 0);
  }
  __syncthreads();  // all reads of tA done; safe to overwrite

  // gelu -> write messages back into tA (bf16)
#pragma unroll
  for (int r4 = 0; r4 < 4; ++r4)
#pragma unroll
    for (int c = 0; c < 4; ++c) {
      int col = w * 64 + c * 16 + lr;
#pragma unroll
      for (int j = 0; j < 4; ++j) {
        int row = r4 * 16 + lh * 4 + j;
        *(unsigned short*)((char*)tA + SWZ(row, row * 512 + col * 2)) =
            f2bf(gelu_f(acc[r4][c][j]));
      }
    }
  __syncthreads();

  // two independent 32-row segmented column reductions (halved serial chain;
  // a dst segment spanning row 31/32 just issues one extra atomic)
  {
    const int col = tid;
    const int r0 = 0, r1 = 32;
    float runA = 0.f, runB = 0.f;
    int curA = dstS[r0], curB = dstS[r1];
#pragma unroll 8
    for (int i = 0; i < 32; ++i) {
      int dA = dstS[r0 + i];
      int dB = dstS[r1 + i];
      float vA = bf2f(*(const unsigned short*)((const char*)tA +
                      SWZ(r0 + i, (r0 + i) * 512 + col * 2)));
      float vB = bf2f(*(const unsigned short*)((const char*)tA +
                      SWZ(r1 + i, (r1 + i) * 512 + col * 2)));
      if (dA != curA) { atomicAdd(&S[(size_t)curA * 256 + col], runA); runA = 0.f; curA = dA; }
      if (dB != curB) { atomicAdd(&S[(size_t)curB * 256 + col], runB); runB = 0.f; curB = dB; }
      runA += vA;
      runB += vB;
    }
    atomicAdd(&S[(size_t)curA * 256 + col], runA);
    atomicAdd(&S[(size_t)curB * 256 + col], runB);
  }
}

// ---------------------------------------------------------------- node kernel
// 64 nodes/block: A2 = S/max(deg,1); agg = A2@W2m + (deg>0)b2m;
// H = gelu(agg@W1u + b1u); U = H@W2u + b2u; out = LN(node + U)*gamma + beta.
__global__ __launch_bounds__(256) void node_kernel(
    const float* __restrict__ node, const float* __restrict__ S, const int* __restrict__ rptr,
    const unsigned short* __restrict__ P2m, const float* __restrict__ b2m,
    const unsigned short* __restrict__ P1u, const float* __restrict__ b1u,
    const unsigned short* __restrict__ P2u, const float* __restrict__ b2u,
    const float* __restrict__ gamma, const float* __restrict__ beta,
    float* __restrict__ out) {
  __shared__ unsigned short tAB[2][64 * 256];  // 64 KB: [0]=A2, [1]=agg; reused as fp32 U
  __shared__ unsigned short tH[64 * 512];      // 64 KB
  __shared__ float fmu[64], frs[64], fflag[64];
  float* tU = (float*)tAB;
  const int tid = threadIdx.x;
  const int n0 = blockIdx.x * 64;
  const int r = tid >> 2;
  const int cs = (tid & 3) * 64;
  const int n = n0 + r;
  const bool valid = n < N_NODES;
  {
    int dgi = valid ? (rptr[n + 1] - rptr[n]) : 0;
    float dg = (float)dgi;
    float rec = 1.0f / fmaxf(dg, 1.0f);
    if ((tid & 3) == 0) fflag[r] = (dgi > 0) ? 1.0f : 0.0f;
    const float4* sp = (const float4*)(S + (size_t)n * 256 + cs);
#pragma unroll
    for (int i = 0; i < 8; ++i) {
      float4 a = valid ? sp[2 * i]     : make_float4(0.f, 0.f, 0.f, 0.f);
      float4 b = valid ? sp[2 * i + 1] : make_float4(0.f, 0.f, 0.f, 0.f);
      uint4 p;
      p.x = pk2(a.x * rec, a.y * rec);
      p.y = pk2(a.z * rec, a.w * rec);
      p.z = pk2(b.x * rec, b.y * rec);
      p.w = pk2(b.z * rec, b.w * rec);
      *(uint4*)((char*)tAB[0] + SWZ(r, r * 512 + (cs + i * 8) * 2)) = p;
    }
  }
  __syncthreads();
  const int w = tid >> 6, l = tid & 63, lr = l & 15, lh = l >> 4;

  // ---- GEMM1: agg = A2 @ W2m + flag*b2m -> tAB[1] (bf16)
  {
    f32x4 acc[4][4];
#pragma unroll
    for (int r4 = 0; r4 < 4; ++r4)
#pragma unroll
      for (int c = 0; c < 4; ++c) acc[r4][c] = f32x4{0.f, 0.f, 0.f, 0.f};
#pragma unroll
    for (int t = 0; t < 8; ++t) {
      short8 af[4], bfr[4];
#pragma unroll
      for (int r4 = 0; r4 < 4; ++r4) {
        int row = r4 * 16 + lr;
        af[r4] = *(const short8*)((const char*)tAB[0] + SWZ(row, row * 512 + t * 64 + lh * 16));
      }
#pragma unroll
      for (int c = 0; c < 4; ++c)
        bfr[c] = *(const short8*)(P2m + (size_t)(((w * 4 + c) * 8 + t) * 512 + l * 8));
#pragma unroll
      for (int r4 = 0; r4 < 4; ++r4)
#pragma unroll
        for (int c = 0; c < 4; ++c)
          acc[r4][c] = __builtin_amdgcn_mfma_f32_16x16x32_bf16(af[r4], bfr[c], acc[r4][c], 0, 0, 0);
    }
#pragma unroll
    for (int r4 = 0; r4 < 4; ++r4)
#pragma unroll
      for (int c = 0; c < 4; ++c) {
        int col = w * 64 + c * 16 + lr;
        float bm = b2m[col];
#pragma unroll
        for (int j = 0; j < 4; ++j) {
          int row = r4 * 16 + lh * 4 + j;
          float v = acc[r4][c][j] + fflag[row] * bm;
          *(unsigned short*)((char*)tAB[1] + SWZ(row, row * 512 + col * 2)) = f2bf(v);
        }
      }
  }
  __syncthreads();

  // ---- GEMM2: H = gelu(agg @ W1u + b1u) -> tH (64x512 bf16)
  {
    f32x4 acc[4][8];
#pragma unroll
    for (int r4 = 0; r4 < 4; ++r4)
#pragma unroll
      for (int c = 0; c < 8; ++c) acc[r4][c] = f32x4{0.f, 0.f, 0.f, 0.f};
#pragma unroll
    for (int t = 0; t < 8; ++t) {
      short8 af[4], bfr[8];
#pragma unroll
      for (int r4 = 0; r4 < 4; ++r4) {
        int row = r4 * 16 + lr;
        af[r4] = *(const short8*)((const char*)tAB[1] + SWZ(row, row * 512 + t * 64 + lh * 16));
      }
#pragma unroll
      for (int c = 0; c < 8; ++c)
        bfr[c] = *(const short8*)(P1u + (size_t)(((w * 8 + c) * 8 + t) * 512 + l * 8));
#pragma unroll
      for (int r4 = 0; r4 < 4; ++r4)
#pragma unroll
        for (int c = 0; c < 8; ++c)
          acc[r4][c] = __builtin_amdgcn_mfma_f32_16x16x32_bf16(af[r4], bfr[c], acc[r4][c], 0, 0, 0);
    }
#pragma unroll
    for (int r4 = 0; r4 < 4; ++r4)
#pragma unroll
      for (int c = 0; c < 8; ++c) {
        int col = w * 128 + c * 16 + lr;
        float b1 = b1u[col];
#pragma unroll
        for (int j = 0; j < 4; ++j) {
          int row = r4 * 16 + lh * 4 + j;
          float v = gelu_f(acc[r4][c][j] + b1);
          *(unsigned short*)((char*)tH + SWZ(row, row * 1024 + col * 2)) = f2bf(v);
        }
      }
  }
  __syncthreads();

  // ---- GEMM3: U = H @ W2u + b2u -> tU (fp32, SWZU)  [tAB dead -> reuse as tU]
  {
    f32x4 acc[4][4];
#pragma unroll
    for (int r4 = 0; r4 < 4; ++r4)
#pragma unroll
      for (int c = 0; c < 4; ++c) acc[r4][c] = f32x4{0.f, 0.f, 0.f, 0.f};
#pragma unroll
    for (int t = 0; t < 16; ++t) {
      short8 af[4], bfr[4];
#pragma unroll
      for (int r4 = 0; r4 < 4; ++r4) {
        int row = r4 * 16 + lr;
        af[r4] = *(const short8*)((const char*)tH + SWZ(row, row * 1024 + t * 64 + lh * 16));
      }
#pragma unroll
      for (int c = 0; c < 4; ++c)
        bfr[c] = *(const short8*)(P2u + (size_t)(((w * 4 + c) * 16 + t) * 512 + l * 8));
#pragma unroll
      for (int r4 = 0; r4 < 4; ++r4)
#pragma unroll
        for (int c = 0; c < 4; ++c)
          acc[r4][c] = __builtin_amdgcn_mfma_f32_16x16x32_bf16(af[r4], bfr[c], acc[r4][c], 0, 0, 0);
    }
#pragma unroll
    for (int r4 = 0; r4 < 4; ++r4)
#pragma unroll
      for (int c = 0; c < 4; ++c) {
        int col = w * 64 + c * 16 + lr;
        float b2 = b2u[col];
#pragma unroll
        for (int j = 0; j < 4; ++j) {
          int row = r4 * 16 + lh * 4 + j;
          *(float*)((char*)tU + SWZU(row * 1024 + col * 4)) = acc[r4][c][j] + b2;
        }
      }
  }
  __syncthreads();

  // ---- residual + LayerNorm stats
  {
    float sum = 0.f, sq = 0.f;
#pragma unroll
    for (int i = 0; i < 16; ++i) {
      int byte = SWZU(r * 1024 + (cs + i * 4) * 4);
      float4 v = *(float4*)((char*)tU + byte);
      if (valid) {
        const float4 nb = *(const float4*)(node + (size_t)n * 256 + cs + i * 4);
        v.x += nb.x; v.y += nb.y; v.z += nb.z; v.w += nb.w;
        *(float4*)((char*)tU + byte) = v;
      }
      sum += v.x + v.y + v.z + v.w;
      sq += v.x * v.x + v.y * v.y + v.z * v.z + v.w * v.w;
    }
    sum += __shfl_xor(sum, 1); sum += __shfl_xor(sum, 2);
    sq  += __shfl_xor(sq, 1);  sq  += __shfl_xor(sq, 2);
    if ((tid & 3) == 0) {
      float mu = sum * (1.0f / 256.0f);
      fmu[r] = mu;
      frs[r] = rsqrtf(fmaxf(sq * (1.0f / 256.0f) - mu * mu, 0.0f) + 1e-5f);
    }
  }
  __syncthreads();
#pragma unroll
  for (int i = 0; i < 16; ++i) {
    int f4 = i * 256 + tid;
    int row = f4 >> 6;
    int c4 = f4 & 63;
    int nn = n0 + row;
    if (nn < N_NODES) {
      float4 v = *(float4*)((char*)tU + SWZU(row * 1024 + c4 * 16));
      float mu = fmu[row], rs = frs[row];
      float4 g  = *(const float4*)(gamma + c4 * 4);
      float4 bt = *(const float4*)(beta + c4 * 4);
      float4 o;
      o.x = (v.x - mu) * rs * g.x + bt.x;
      o.y = (v.y - mu) * rs * g.y + bt.y;
      o.z = (v.z - mu) * rs * g.z + bt.z;
      o.w = (v.w - mu) * rs * g.w + bt.w;
      *(float4*)(out + (size_t)nn * 256 + c4 * 4) = o;
    }
  }
}

// ---------------------------------------------------------------- launch
extern "C" void kernel_launch(void* const* d_in, const int* in_sizes, int n_in,
                              void* d_out, int out_size, void* d_ws, size_t ws_size,
                              hipStream_t stream) {
  const float* node = (const float*)d_in[0];
  const int* eidx = (const int*)d_in[1];   // harness delivers integer inputs as int32
  const float* eemb = (const float*)d_in[2];
  const float* W1m = (const float*)d_in[3];
  const float* b1m = (const float*)d_in[4];
  const float* W2m = (const float*)d_in[5];
  const float* b2m = (const float*)d_in[6];
  const float* W1u = (const float*)d_in[7];
  const float* b1u = (const float*)d_in[8];
  const float* W2u = (const float*)d_in[9];
  const float* b2u = (const float*)d_in[10];
  const float* gamma = (const float*)d_in[11];
  const float* beta = (const float*)d_in[12];
  float* out = (float*)d_out;  // doubles as the scatter accumulator S [N,256] f32

  char* ws = (char*)d_ws;
  int* cnt  = (int*)ws;                                   // 80000 B
  int* rptr = (int*)(ws + 81920);                         // 80004 B
  int* cur  = (int*)(ws + 163840);                        // 80000 B
  int* perm = (int*)(ws + 245760);                        // 1280000 B
  unsigned short* P1m = (unsigned short*)(ws + 1525760);  // 131072 B
  unsigned short* P2m = (unsigned short*)(ws + 1656832);  // 131072 B
  unsigned short* P1u = (unsigned short*)(ws + 1787904);  // 262144 B
  unsigned short* P2u = (unsigned short*)(ws + 2050048);  // 262144 B
  const int* src = eidx;
  const int* dst = eidx + N_EDGES;

  zero_kernel<<<N_NODES * 64 / 256, 256, 0, stream>>>((float4*)out, (int4*)cnt);
  pack_kernel<<<393216 / 256, 256, 0, stream>>>(W1m, W2m, W1u, W2u, P1m, P2m, P1u, P2u);
  hist_kernel<<<N_EDGES / 256, 256, 0, stream>>>(dst, cnt);
  scan_kernel<<<1, 1024, 0, stream>>>(cnt, rptr, cur);
  scatter_kernel<<<N_EDGES / 256, 256, 0, stream>>>(dst, cur, perm);
  edge_kernel<<<N_EDGES / 64, 256, 0, stream>>>(node, eemb, src, dst, perm, P1m, b1m, out);
  node_kernel<<<(N_NODES + 63) / 64, 256, 0, stream>>>(node, out, rptr, P2m, b2m,
                                                       P1u, b1u, P2u, b2u, gamma, beta, out);
}